// Round 1
// baseline (2942.108 us; speedup 1.0000x reference)
//
#include <hip/hip_runtime.h>
#include <math.h>

// ---------------------------------------------------------------------------
// 2-layer GCN:  out = GCNConv(relu(GCNConv(x, W1, b1)), W2, b2)
// Factorization: g = (x@W) * dinv[row];  agg[d] = g[d] + sum_{s in in(d)} g[s];
//                out[d] = agg[d]*dinv[d] + b   (dinv = rsqrt(indeg+1))
//
// R1-R5 history: bucket sort -> LDS sort -> bf16 G rows -> dwordx4 gathers
//   (342 us, aggregate 2x60 us, FETCH 162 MB @ 2.7 TB/s fetch path).
// R6: aggregate is fetch-path bound; G (12.8MB) doesn't fit 4MB/XCD L2 ->
//   36% miss on random gathers. New: range-major edges (13 ranges x 8192 src
//   nodes = 1MB G-slice), block-per-bucket aggregate with 133KB LDS f32
//   accumulator + ds_add_f32. Per-XCD working set ~1-2MB -> L2 resident.
//   csr_sort DELETED (LDS-atomic acc needs no per-node grouping); replaced by
//   16-bin range_scatter which also emits dinv.
// ---------------------------------------------------------------------------

#define BKT_SHIFT 9               // 512 nodes per bucket
#define BKT_NODES 512
#define NBSH      256             // >= bucket count (196)
#define CHUNK     8192            // edges per bucket_bin/coarse_hist block
#define MAXB      20480           // max edges/bucket (mean ~16.3k)
#define RSH       13              // src range shift: ranges of 8192 nodes
#define NR        16              // range bins (13 used for N=100000)
#define ACC_STRIDE 65             // LDS acc row stride (bank spread)

typedef unsigned short ushort_t;

static __device__ __forceinline__ unsigned short f2bf(float f) {
    unsigned u = __float_as_uint(f);
    unsigned r = (u + 0x7FFFu + ((u >> 16) & 1u)) >> 16;   // RNE
    return (unsigned short)r;
}
static __device__ __forceinline__ float bf_lo(unsigned u) {
    return __uint_as_float(u << 16);
}
static __device__ __forceinline__ float bf_hi(unsigned u) {
    return __uint_as_float(u & 0xFFFF0000u);
}

struct ushort4_t { unsigned short x, y, z, w; };

__global__ __launch_bounds__(256) void zero_small(int* __restrict__ bhist,
                                                  int* __restrict__ bcur,
                                                  int* __restrict__ rofs,
                                                  int NB, int E) {
    int t = threadIdx.x;
    bhist[t] = 0;
    bcur[t]  = 0;
    if (t == 0) rofs[NB * NR] = E;   // sentinel: end of last bucket's last range
}

// Coarse histogram over 196 buckets: LDS accumulate, 196 global atomics/block.
__global__ __launch_bounds__(256) void coarse_hist(const int* __restrict__ dst,
                                                   int* __restrict__ bhist,
                                                   int E, int NB) {
    __shared__ int h[NBSH];
    const int t  = threadIdx.x;
    const int e0 = blockIdx.x * CHUNK;
    const int n  = min(CHUNK, E - e0);
    h[t] = 0;
    __syncthreads();
    for (int i = t; i < n; i += 256) atomicAdd(&h[dst[e0 + i] >> BKT_SHIFT], 1);
    __syncthreads();
    if (t < NB && h[t] > 0) atomicAdd(&bhist[t], h[t]);
}

// Exclusive scan of bucket counts -> boffs[0..NB] (boffs[NB] = E).
__global__ __launch_bounds__(256) void scan196(const int* __restrict__ bhist,
                                               int* __restrict__ boffs, int NB, int E) {
    __shared__ int sh[256];
    int t = threadIdx.x;
    int orig = (t < NB) ? bhist[t] : 0;
    sh[t] = orig;
    __syncthreads();
    for (int d = 1; d < 256; d <<= 1) {
        int u = (t >= d) ? sh[t - d] : 0;
        __syncthreads();
        sh[t] += u;
        __syncthreads();
    }
    if (t < NB) boffs[t] = sh[t] - orig;  // exclusive
    if (t == NB) boffs[NB] = E;
    if (t == 255 && NB < 255) boffs[NB] = E;
}

// Phase A: bin edges into buckets. Packed pair: (dst&511)<<17 | src  (src<2^17).
__global__ __launch_bounds__(256) void bucket_bin(const int* __restrict__ src,
                                                  const int* __restrict__ dst,
                                                  const int* __restrict__ boffs,
                                                  int* __restrict__ bcur,
                                                  unsigned* __restrict__ pairs,
                                                  int E, int NB) {
    __shared__ unsigned stag[CHUNK];   // 32KB
    __shared__ int hist[NBSH];
    __shared__ int lofs[NBSH];
    __shared__ int lcur[NBSH];
    __shared__ int gbase[NBSH];
    const int t  = threadIdx.x;
    const int e0 = blockIdx.x * CHUNK;
    const int n  = min(CHUNK, E - e0);

    for (int i = t; i < NBSH; i += 256) hist[i] = 0;
    __syncthreads();
    for (int i = t; i < n; i += 256) atomicAdd(&hist[dst[e0 + i] >> BKT_SHIFT], 1);
    __syncthreads();
    int v = hist[t];
    lofs[t] = v;
    __syncthreads();
    for (int d = 1; d < 256; d <<= 1) {
        int u = (t >= d) ? lofs[t - d] : 0;
        __syncthreads();
        lofs[t] += u;
        __syncthreads();
    }
    if (t < NB) {
        lcur[t]  = lofs[t] - v;
        gbase[t] = (v > 0) ? boffs[t] + atomicAdd(&bcur[t], v) : 0;
    }
    __syncthreads();
    for (int i = t; i < n; i += 256) {
        int d = dst[e0 + i];
        int s = src[e0 + i];
        int b = d >> BKT_SHIFT;
        int p = atomicAdd(&lcur[b], 1);
        stag[p] = ((unsigned)(d & (BKT_NODES - 1)) << 17) | (unsigned)s;
    }
    __syncthreads();
    // copy-out: wave-per-bucket (parallel across the 4 waves, 64-lane runs)
    const int wv = t >> 6, ln = t & 63;
    for (int b = wv; b < NB; b += 4) {
        int cb = hist[b];
        if (cb == 0) continue;
        int lo = lofs[b] - cb;
        int gb = gbase[b];
        for (int i = ln; i < cb; i += 64) pairs[gb + i] = stag[lo + i];
    }
}

// Phase B (replaces csr_sort): per-bucket 16-bin counting scatter by src-range
// (r = src>>13). Emits range-major pairs2, per-(bucket,range) offsets rofs,
// and per-node dinv (from the in-degree histogram it needs anyway).
__global__ __launch_bounds__(1024) void range_scatter(const unsigned* __restrict__ pairs,
                                                      const int* __restrict__ boffs,
                                                      unsigned* __restrict__ pairs2,
                                                      int* __restrict__ rofs,
                                                      float* __restrict__ dinv,
                                                      int N) {
    extern __shared__ unsigned st[];   // MAXB entries (80KB)
    __shared__ int rh[NR];
    __shared__ int rex[NR + 1];
    __shared__ int rcur[NR];
    __shared__ int nh[BKT_NODES];
    const int b    = blockIdx.x;
    const int t    = threadIdx.x;
    const int n0   = b << BKT_SHIFT;
    const int base = boffs[b];
    const int ne   = boffs[b + 1] - base;

    if (t < NR) rh[t] = 0;
    if (t < BKT_NODES) nh[t] = 0;
    __syncthreads();
    for (int i = t; i < ne; i += 1024) {
        unsigned p = pairs[base + i];
        atomicAdd(&rh[(p & 0x1FFFFu) >> RSH], 1);
        atomicAdd(&nh[p >> 17], 1);
    }
    __syncthreads();
    if (t == 0) {
        int s = 0;
        for (int r = 0; r < NR; ++r) { rex[r] = s; s += rh[r]; }
        rex[NR] = s;
    }
    if (t < BKT_NODES) {
        int node = n0 + t;
        if (node < N) dinv[node] = rsqrtf((float)(nh[t] + 1));
    }
    __syncthreads();
    if (t < NR) {
        rcur[t] = rex[t];
        rofs[b * NR + t] = base + rex[t];
    }
    __syncthreads();
    const bool fit = (ne <= MAXB);
    for (int i = t; i < ne; i += 1024) {
        unsigned p = pairs[base + i];
        int pos = atomicAdd(&rcur[(p & 0x1FFFFu) >> RSH], 1);
        if (fit) st[pos] = p;
        else     pairs2[base + pos] = p;   // safety fallback (uncoalesced)
    }
    if (fit) {
        __syncthreads();
        for (int i = t; i < ne; i += 1024) pairs2[base + i] = st[i];
    }
}

// G[row] = bf16( (X[row] @ W) * dinv[row] ).  X:[N,K] f32, W:[K,64], G:[N,64] bf16.
template <int K>
__global__ __launch_bounds__(256) void gemm_scale(const float* __restrict__ X,
                                                  const float* __restrict__ W,
                                                  const float* __restrict__ dinv,
                                                  ushort_t* __restrict__ G, int N) {
    __shared__ float Ws[K * 64];
    __shared__ float Xs[32][K + 1];
    const int t  = threadIdx.x;
    const int r0 = blockIdx.x * 32;

    for (int i = t; i < K * 16; i += 256)
        ((float4*)Ws)[i] = ((const float4*)W)[i];

    for (int i = t; i < 32 * (K / 4); i += 256) {
        int row = i / (K / 4);
        int kk  = (i % (K / 4)) * 4;
        int gr  = r0 + row;
        float4 v = make_float4(0.f, 0.f, 0.f, 0.f);
        if (gr < N) v = *(const float4*)(X + (size_t)gr * K + kk);
        Xs[row][kk + 0] = v.x; Xs[row][kk + 1] = v.y;
        Xs[row][kk + 2] = v.z; Xs[row][kk + 3] = v.w;
    }
    __syncthreads();

    const int cg = (t & 15) * 4;
    const int ry = t >> 4;
    float4 a0 = make_float4(0.f, 0.f, 0.f, 0.f);
    float4 a1 = make_float4(0.f, 0.f, 0.f, 0.f);
#pragma unroll 8
    for (int k = 0; k < K; ++k) {
        float4 w = *(const float4*)&Ws[k * 64 + cg];
        float x0 = Xs[ry][k];
        float x1 = Xs[ry + 16][k];
        a0.x = fmaf(x0, w.x, a0.x); a0.y = fmaf(x0, w.y, a0.y);
        a0.z = fmaf(x0, w.z, a0.z); a0.w = fmaf(x0, w.w, a0.w);
        a1.x = fmaf(x1, w.x, a1.x); a1.y = fmaf(x1, w.y, a1.y);
        a1.z = fmaf(x1, w.z, a1.z); a1.w = fmaf(x1, w.w, a1.w);
    }

    int row0 = r0 + ry;
    if (row0 < N) {
        float s = dinv[row0];
        ushort4_t o = { f2bf(a0.x * s), f2bf(a0.y * s), f2bf(a0.z * s), f2bf(a0.w * s) };
        *(ushort4_t*)(G + (size_t)row0 * 64 + cg) = o;
    }
    int row1 = r0 + ry + 16;
    if (row1 < N) {
        float s = dinv[row1];
        ushort4_t o = { f2bf(a1.x * s), f2bf(a1.y * s), f2bf(a1.z * s), f2bf(a1.w * s) };
        *(ushort4_t*)(G + (size_t)row1 * 64 + cg) = o;
    }
}

// LDS accumulator column swizzle: col (sub*8 + i) lives at elem (i*8 + sub)
// of the node's ACC_STRIDE row -> ds_add banks = (nl + 8i + sub) % 32: 8
// contiguous subs x random nl starts ~> <=4-way conflicts (cheap).
#define ATOM8(ap, v)                                                     \
    atomicAdd((ap) + 0,  bf_lo((v).x)); atomicAdd((ap) + 8,  bf_hi((v).x)); \
    atomicAdd((ap) + 16, bf_lo((v).y)); atomicAdd((ap) + 24, bf_hi((v).y)); \
    atomicAdd((ap) + 32, bf_lo((v).z)); atomicAdd((ap) + 40, bf_hi((v).z)); \
    atomicAdd((ap) + 48, bf_lo((v).w)); atomicAdd((ap) + 56, bf_hi((v).w));

// Block-per-bucket aggregate: walks src ranges in lockstep (196 co-resident
// blocks, 1/CU) so each XCD's gather working set is one ~1MB G-slice.
// grp = t>>3 picks one of 128 parallel edges, sub = t&7 the 16B row chunk.
__global__ __launch_bounds__(1024) void aggregate3(const ushort_t* __restrict__ G,
                                                   const unsigned* __restrict__ pairs2,
                                                   const int* __restrict__ rofs,
                                                   const float* __restrict__ dinv,
                                                   const float* __restrict__ bias,
                                                   float* __restrict__ out, int N,
                                                   int do_relu) {
    extern __shared__ float accf[];    // BKT_NODES * ACC_STRIDE = 133120 B
    const int b  = blockIdx.x;
    const int t  = threadIdx.x;
    const int n0 = b << BKT_SHIFT;

    for (int i = t; i < BKT_NODES * ACC_STRIDE; i += 1024) accf[i] = 0.f;
    __syncthreads();

    const int grp = t >> 3;   // 0..127: which edge of the batch
    const int sub = t & 7;    // which 16B chunk (8 bf16 cols) of the 128B row

    for (int r = 0; r < NR; ++r) {
        const int s = rofs[b * NR + r];
        const int e = rofs[b * NR + r + 1];
        for (int i0 = s; i0 < e; i0 += 256) {
            int ia = i0 + grp;
            int ib = ia + 128;
            if (ib < e) {
                unsigned pa = pairs2[ia];
                unsigned pb = pairs2[ib];
                uint4 va = *(const uint4*)(G + (size_t)(pa & 0x1FFFFu) * 64 + sub * 8);
                uint4 vb = *(const uint4*)(G + (size_t)(pb & 0x1FFFFu) * 64 + sub * 8);
                float* aa = &accf[(pa >> 17) * ACC_STRIDE + sub];
                float* ab = &accf[(pb >> 17) * ACC_STRIDE + sub];
                ATOM8(aa, va);
                ATOM8(ab, vb);
            } else if (ia < e) {
                unsigned pa = pairs2[ia];
                uint4 va = *(const uint4*)(G + (size_t)(pa & 0x1FFFFu) * 64 + sub * 8);
                float* aa = &accf[(pa >> 17) * ACC_STRIDE + sub];
                ATOM8(aa, va);
            }
        }
        __syncthreads();   // range lockstep: keep the block on one G-slice
    }

    // epilogue: out = (acc + G[node]) * dinv + bias  (self-loop folded in)
    for (int c = 0; c < 4; ++c) {
        int nl = c * 128 + (t >> 3);
        int node = n0 + nl;
        if (node >= N) continue;
        uint4 gv = *(const uint4*)(G + (size_t)node * 64 + sub * 8);
        float d = dinv[node];
        float4 bl0 = *(const float4*)(bias + sub * 8);
        float4 bl1 = *(const float4*)(bias + sub * 8 + 4);
        const float* ap = &accf[nl * ACC_STRIDE + sub];
        float4 o0 = make_float4(fmaf(ap[0]  + bf_lo(gv.x), d, bl0.x),
                                fmaf(ap[8]  + bf_hi(gv.x), d, bl0.y),
                                fmaf(ap[16] + bf_lo(gv.y), d, bl0.z),
                                fmaf(ap[24] + bf_hi(gv.y), d, bl0.w));
        float4 o1 = make_float4(fmaf(ap[32] + bf_lo(gv.z), d, bl1.x),
                                fmaf(ap[40] + bf_hi(gv.z), d, bl1.y),
                                fmaf(ap[48] + bf_lo(gv.w), d, bl1.z),
                                fmaf(ap[56] + bf_hi(gv.w), d, bl1.w));
        if (do_relu) {
            o0.x = fmaxf(o0.x, 0.f); o0.y = fmaxf(o0.y, 0.f);
            o0.z = fmaxf(o0.z, 0.f); o0.w = fmaxf(o0.w, 0.f);
            o1.x = fmaxf(o1.x, 0.f); o1.y = fmaxf(o1.y, 0.f);
            o1.z = fmaxf(o1.z, 0.f); o1.w = fmaxf(o1.w, 0.f);
        }
        *(float4*)(out + (size_t)node * 64 + sub * 8)     = o0;
        *(float4*)(out + (size_t)node * 64 + sub * 8 + 4) = o1;
    }
}

extern "C" void kernel_launch(void* const* d_in, const int* in_sizes, int n_in,
                              void* d_out, int out_size, void* d_ws, size_t ws_size,
                              hipStream_t stream) {
    const float* x  = (const float*)d_in[0];
    const int*   ei = (const int*)d_in[1];
    const float* W1 = (const float*)d_in[2];
    const float* b1 = (const float*)d_in[3];
    const float* W2 = (const float*)d_in[4];
    const float* b2 = (const float*)d_in[5];
    float* out = (float*)d_out;

    const int IN_CH = 128;
    const int N = in_sizes[0] / IN_CH;   // 100000
    const int E = in_sizes[1] / 2;       // 3200000
    const int* src = ei;
    const int* dst = ei + E;
    const int NB = (N + BKT_NODES - 1) >> BKT_SHIFT;  // 196

    char* ws = (char*)d_ws;
    size_t off = 0;
    auto take = [&](size_t bytes) -> char* {
        char* p = ws + off;
        off += (bytes + 255) & ~(size_t)255;
        return p;
    };
    float*    dinv   = (float*)take((size_t)N * 4);
    int*      bhist  = (int*)take(NBSH * 4);
    int*      boffs  = (int*)take((NBSH + 1) * 4);
    int*      bcur   = (int*)take(NBSH * 4);
    int*      rofs   = (int*)take(((size_t)NB * NR + 1) * 4);
    unsigned* pairs2 = (unsigned*)take((size_t)E * 4);
    ushort_t* g      = (ushort_t*)take((size_t)E * 4);  // >= N*64*2; aliases pairs
    float*    a1     = (float*)take((size_t)N * 64 * 4);
    unsigned* pairs  = (unsigned*)g;  // pairs dead before gemm writes g

    const int nbC = (E + CHUNK - 1) / CHUNK;
    const unsigned ACC_BYTES = BKT_NODES * ACC_STRIDE * 4;   // 133120

    zero_small<<<1, 256, 0, stream>>>(bhist, bcur, rofs, NB, E);
    coarse_hist<<<nbC, 256, 0, stream>>>(dst, bhist, E, NB);
    scan196<<<1, 256, 0, stream>>>(bhist, boffs, NB, E);
    bucket_bin<<<nbC, 256, 0, stream>>>(src, dst, boffs, bcur, pairs, E, NB);
    range_scatter<<<NB, 1024, MAXB * 4, stream>>>(pairs, boffs, pairs2, rofs, dinv, N);

    // layer 1
    gemm_scale<128><<<(N + 31) / 32, 256, 0, stream>>>(x, W1, dinv, g, N);
    aggregate3<<<NB, 1024, ACC_BYTES, stream>>>(g, pairs2, rofs, dinv, b1, a1, N, 1);
    // layer 2
    gemm_scale<64><<<(N + 31) / 32, 256, 0, stream>>>(a1, W2, dinv, g, N);
    aggregate3<<<NB, 1024, ACC_BYTES, stream>>>(g, pairs2, rofs, dinv, b2, out, N, 0);
}

// Round 2
// 566.527 us; speedup vs baseline: 5.1932x; 5.1932x over previous
//
#include <hip/hip_runtime.h>
#include <math.h>

// ---------------------------------------------------------------------------
// 2-layer GCN:  out = GCNConv(relu(GCNConv(x, W1, b1)), W2, b2)
// Factorization: g = (x@W) * dinv[row];  agg[d] = g[d] + sum_{s in in(d)} g[s];
//                out[d] = agg[d]*dinv[d] + b   (dinv = rsqrt(indeg+1))
//
// R1-R5: bucket sort -> LDS sort -> bf16 G rows -> dwordx4 gathers (342us,
//   aggregate 2x60us, FETCH 162MB: G 12.8MB misses 4MB/XCD L2 on random gather).
// R6: range-major edges + 133KB LDS f32 accumulator w/ atomicAdd: FETCH fixed
//   (162->61MB, locality theory confirmed) but dur 60->1366us, VALUBusy 0.9%:
//   generic-pointer float LDS atomics are a disaster (flat/CAS path). REVERTED.
// R7: keep range-major gathers, kill all atomics: sort by (range, dst-node)
//   so each 8-lane group owns 4 fixed dst nodes and accumulates in REGISTERS
//   (acc[4][8], no LDS in hot loop). Segment bounds come free from the sort's
//   bin-offset scan (rofs2: per (bucket,range,node) start; end = next start).
// ---------------------------------------------------------------------------

#define BKT_SHIFT 9               // 512 nodes per bucket
#define BKT_NODES 512
#define NBSH      256             // >= bucket count (196)
#define CHUNK     8192            // edges per bucket_bin/coarse_hist block
#define MAXB      20480           // max edges/bucket (mean ~16.3k)
#define RSH       13              // src range shift: ranges of 8192 nodes (1MB of G)
#define NBIN_MAX  8192            // 16 ranges * 512 nodes (13 used)

typedef unsigned short ushort_t;

static __device__ __forceinline__ unsigned short f2bf(float f) {
    unsigned u = __float_as_uint(f);
    unsigned r = (u + 0x7FFFu + ((u >> 16) & 1u)) >> 16;   // RNE
    return (unsigned short)r;
}
static __device__ __forceinline__ float bf_lo(unsigned u) {
    return __uint_as_float(u << 16);
}
static __device__ __forceinline__ float bf_hi(unsigned u) {
    return __uint_as_float(u & 0xFFFF0000u);
}

struct ushort4_t { unsigned short x, y, z, w; };

__global__ __launch_bounds__(256) void zero_small(int* __restrict__ bhist,
                                                  int* __restrict__ bcur,
                                                  int* __restrict__ rofs2,
                                                  size_t sentinel_idx, int E) {
    int t = threadIdx.x;
    bhist[t] = 0;
    bcur[t]  = 0;
    if (t == 0) rofs2[sentinel_idx] = E;   // end of last bucket's last bin
}

// Coarse histogram over 196 buckets: LDS accumulate, 196 global atomics/block.
__global__ __launch_bounds__(256) void coarse_hist(const int* __restrict__ dst,
                                                   int* __restrict__ bhist,
                                                   int E, int NB) {
    __shared__ int h[NBSH];
    const int t  = threadIdx.x;
    const int e0 = blockIdx.x * CHUNK;
    const int n  = min(CHUNK, E - e0);
    h[t] = 0;
    __syncthreads();
    for (int i = t; i < n; i += 256) atomicAdd(&h[dst[e0 + i] >> BKT_SHIFT], 1);
    __syncthreads();
    if (t < NB && h[t] > 0) atomicAdd(&bhist[t], h[t]);
}

// Exclusive scan of bucket counts -> boffs[0..NB] (boffs[NB] = E).
__global__ __launch_bounds__(256) void scan196(const int* __restrict__ bhist,
                                               int* __restrict__ boffs, int NB, int E) {
    __shared__ int sh[256];
    int t = threadIdx.x;
    int orig = (t < NB) ? bhist[t] : 0;
    sh[t] = orig;
    __syncthreads();
    for (int d = 1; d < 256; d <<= 1) {
        int u = (t >= d) ? sh[t - d] : 0;
        __syncthreads();
        sh[t] += u;
        __syncthreads();
    }
    if (t < NB) boffs[t] = sh[t] - orig;  // exclusive
    if (t == NB) boffs[NB] = E;
    if (t == 255 && NB < 255) boffs[NB] = E;
}

// Phase A: bin edges into buckets. Packed pair: (dst&511)<<17 | src  (src<2^17).
__global__ __launch_bounds__(256) void bucket_bin(const int* __restrict__ src,
                                                  const int* __restrict__ dst,
                                                  const int* __restrict__ boffs,
                                                  int* __restrict__ bcur,
                                                  unsigned* __restrict__ pairs,
                                                  int E, int NB) {
    __shared__ unsigned stag[CHUNK];   // 32KB
    __shared__ int hist[NBSH];
    __shared__ int lofs[NBSH];
    __shared__ int lcur[NBSH];
    __shared__ int gbase[NBSH];
    const int t  = threadIdx.x;
    const int e0 = blockIdx.x * CHUNK;
    const int n  = min(CHUNK, E - e0);

    for (int i = t; i < NBSH; i += 256) hist[i] = 0;
    __syncthreads();
    for (int i = t; i < n; i += 256) atomicAdd(&hist[dst[e0 + i] >> BKT_SHIFT], 1);
    __syncthreads();
    int v = hist[t];
    lofs[t] = v;
    __syncthreads();
    for (int d = 1; d < 256; d <<= 1) {
        int u = (t >= d) ? lofs[t - d] : 0;
        __syncthreads();
        lofs[t] += u;
        __syncthreads();
    }
    if (t < NB) {
        lcur[t]  = lofs[t] - v;
        gbase[t] = (v > 0) ? boffs[t] + atomicAdd(&bcur[t], v) : 0;
    }
    __syncthreads();
    for (int i = t; i < n; i += 256) {
        int d = dst[e0 + i];
        int s = src[e0 + i];
        int b = d >> BKT_SHIFT;
        int p = atomicAdd(&lcur[b], 1);
        stag[p] = ((unsigned)(d & (BKT_NODES - 1)) << 17) | (unsigned)s;
    }
    __syncthreads();
    // copy-out: wave-per-bucket (parallel across the 4 waves, 64-lane runs)
    const int wv = t >> 6, ln = t & 63;
    for (int b = wv; b < NB; b += 4) {
        int cb = hist[b];
        if (cb == 0) continue;
        int lo = lofs[b] - cb;
        int gb = gbase[b];
        for (int i = ln; i < cb; i += 64) pairs[gb + i] = stag[lo + i];
    }
}

// Phase B: per-bucket counting sort by key = (src_range, dst_node).
// Emits pairs2 (src only, range-major node-minor), bin starts rofs2, and dinv.
// nbin = NRU*512 (<= NBIN_MAX).  Int LDS atomics only (native ds_add).
__global__ __launch_bounds__(1024) void range_scatter(const unsigned* __restrict__ pairs,
                                                      const int* __restrict__ boffs,
                                                      unsigned* __restrict__ pairs2,
                                                      int* __restrict__ rofs2,
                                                      float* __restrict__ dinv,
                                                      int N, int NRU) {
    extern __shared__ unsigned st[];   // MAXB entries (80KB)
    __shared__ int hist2[NBIN_MAX];    // 32KB: counts -> exclusive cursors
    __shared__ int sc[1024];           // 4KB scan temp
    const int b    = blockIdx.x;
    const int t    = threadIdx.x;
    const int n0   = b << BKT_SHIFT;
    const int base = boffs[b];
    const int ne   = boffs[b + 1] - base;
    const int nbin = NRU << BKT_SHIFT;

    for (int i = t; i < nbin; i += 1024) hist2[i] = 0;
    __syncthreads();
    for (int i = t; i < ne; i += 1024) {
        unsigned p = pairs[base + i];
        int key = (int)((((p & 0x1FFFFu) >> RSH) << BKT_SHIFT) | (p >> 17));
        atomicAdd(&hist2[key], 1);
    }
    __syncthreads();
    // per-node degree -> dinv (sum the node's column over ranges)
    if (t < BKT_NODES) {
        int node = n0 + t;
        if (node < N) {
            int d = 0;
            for (int r = 0; r < NRU; ++r) d += hist2[(r << BKT_SHIFT) + t];
            dinv[node] = rsqrtf((float)(d + 1));
        }
    }
    __syncthreads();
    // exclusive scan over nbin bins: C bins per thread, then 1024-wide scan
    const int C = (nbin + 1023) >> 10;   // <= 8
    int lv[8];
    int lsum = 0;
#pragma unroll 8
    for (int j = 0; j < 8; ++j) {
        int idx = t * C + j;
        int v = (j < C && idx < nbin) ? hist2[idx] : 0;
        lv[j] = v;
        lsum += v;
    }
    sc[t] = lsum;
    __syncthreads();
    for (int d = 1; d < 1024; d <<= 1) {
        int u = (t >= d) ? sc[t - d] : 0;
        __syncthreads();
        sc[t] += u;
        __syncthreads();
    }
    int run = sc[t] - lsum;   // exclusive over this thread's chunk
    __syncthreads();
#pragma unroll 8
    for (int j = 0; j < 8; ++j) {
        int idx = t * C + j;
        if (j < C && idx < nbin) {
            hist2[idx] = run;                                   // cursor
            rofs2[(size_t)b * nbin + idx] = base + run;          // bin start
            run += lv[j];
        }
    }
    __syncthreads();
    const bool fit = (ne <= MAXB);
    for (int i = t; i < ne; i += 1024) {
        unsigned p = pairs[base + i];
        int key = (int)((((p & 0x1FFFFu) >> RSH) << BKT_SHIFT) | (p >> 17));
        int pos = atomicAdd(&hist2[key], 1);
        unsigned sv = p & 0x1FFFFu;
        if (fit) st[pos] = sv;
        else     pairs2[base + pos] = sv;   // safety fallback (uncoalesced)
    }
    if (fit) {
        __syncthreads();
        for (int i = t; i < ne; i += 1024) pairs2[base + i] = st[i];
    }
}

// G[row] = bf16( (X[row] @ W) * dinv[row] ).  X:[N,K] f32, W:[K,64], G:[N,64] bf16.
template <int K>
__global__ __launch_bounds__(256) void gemm_scale(const float* __restrict__ X,
                                                  const float* __restrict__ W,
                                                  const float* __restrict__ dinv,
                                                  ushort_t* __restrict__ G, int N) {
    __shared__ float Ws[K * 64];
    __shared__ float Xs[32][K + 1];
    const int t  = threadIdx.x;
    const int r0 = blockIdx.x * 32;

    for (int i = t; i < K * 16; i += 256)
        ((float4*)Ws)[i] = ((const float4*)W)[i];

    for (int i = t; i < 32 * (K / 4); i += 256) {
        int row = i / (K / 4);
        int kk  = (i % (K / 4)) * 4;
        int gr  = r0 + row;
        float4 v = make_float4(0.f, 0.f, 0.f, 0.f);
        if (gr < N) v = *(const float4*)(X + (size_t)gr * K + kk);
        Xs[row][kk + 0] = v.x; Xs[row][kk + 1] = v.y;
        Xs[row][kk + 2] = v.z; Xs[row][kk + 3] = v.w;
    }
    __syncthreads();

    const int cg = (t & 15) * 4;
    const int ry = t >> 4;
    float4 a0 = make_float4(0.f, 0.f, 0.f, 0.f);
    float4 a1 = make_float4(0.f, 0.f, 0.f, 0.f);
#pragma unroll 8
    for (int k = 0; k < K; ++k) {
        float4 w = *(const float4*)&Ws[k * 64 + cg];
        float x0 = Xs[ry][k];
        float x1 = Xs[ry + 16][k];
        a0.x = fmaf(x0, w.x, a0.x); a0.y = fmaf(x0, w.y, a0.y);
        a0.z = fmaf(x0, w.z, a0.z); a0.w = fmaf(x0, w.w, a0.w);
        a1.x = fmaf(x1, w.x, a1.x); a1.y = fmaf(x1, w.y, a1.y);
        a1.z = fmaf(x1, w.z, a1.z); a1.w = fmaf(x1, w.w, a1.w);
    }

    int row0 = r0 + ry;
    if (row0 < N) {
        float s = dinv[row0];
        ushort4_t o = { f2bf(a0.x * s), f2bf(a0.y * s), f2bf(a0.z * s), f2bf(a0.w * s) };
        *(ushort4_t*)(G + (size_t)row0 * 64 + cg) = o;
    }
    int row1 = r0 + ry + 16;
    if (row1 < N) {
        float s = dinv[row1];
        ushort4_t o = { f2bf(a1.x * s), f2bf(a1.y * s), f2bf(a1.z * s), f2bf(a1.w * s) };
        *(ushort4_t*)(G + (size_t)row1 * 64 + cg) = o;
    }
}

// Block-per-bucket aggregate, register accumulation, zero LDS in hot loop.
// grp = t>>3 owns dst nodes {grp, 128+grp, 256+grp, 384+grp}; sub = t&7 owns
// 8 bf16 columns [sub*8, sub*8+8). Ranges walked in lockstep (barrier per
// range) so concurrent gathers stay inside one 1MB G-slice per XCD's L2.
__global__ __launch_bounds__(1024) void aggregate4(const ushort_t* __restrict__ G,
                                                   const unsigned* __restrict__ pairs2,
                                                   const int* __restrict__ rofs2,
                                                   const float* __restrict__ dinv,
                                                   const float* __restrict__ bias,
                                                   float* __restrict__ out, int N,
                                                   int do_relu, int NRU) {
    const int b   = blockIdx.x;
    const int t   = threadIdx.x;
    const int n0  = b << BKT_SHIFT;
    const int grp = t >> 3;
    const int sub = t & 7;
    const int nbin = NRU << BKT_SHIFT;
    const size_t rb0 = (size_t)b * nbin;

    float acc[4][8];
#pragma unroll
    for (int c = 0; c < 4; ++c)
#pragma unroll
        for (int k = 0; k < 8; ++k) acc[c][k] = 0.f;

    for (int r = 0; r < NRU; ++r) {
        const int rb = r << BKT_SHIFT;
#pragma unroll
        for (int c = 0; c < 4; ++c) {
            const int nl = (c << 7) + grp;
            const int* rp = rofs2 + rb0 + rb + nl;
            const int s = rp[0];
            const int e = rp[1];   // next bin's start == this bin's end
            for (int j = s; j < e; ++j) {
                unsigned sv = pairs2[j];   // 8 lanes same addr -> broadcast
                const uint4 v = *(const uint4*)(G + ((size_t)sv << 6) + (sub << 3));
                acc[c][0] += bf_lo(v.x); acc[c][1] += bf_hi(v.x);
                acc[c][2] += bf_lo(v.y); acc[c][3] += bf_hi(v.y);
                acc[c][4] += bf_lo(v.z); acc[c][5] += bf_hi(v.z);
                acc[c][6] += bf_lo(v.w); acc[c][7] += bf_hi(v.w);
            }
        }
        __syncthreads();   // range lockstep: keep the block on one G-slice
    }

    // epilogue: out = (acc + G[node]) * dinv + bias  (self-loop folded in)
    float4 bl0 = *(const float4*)(bias + sub * 8);
    float4 bl1 = *(const float4*)(bias + sub * 8 + 4);
#pragma unroll
    for (int c = 0; c < 4; ++c) {
        int nl = (c << 7) + grp;
        int node = n0 + nl;
        if (node >= N) continue;
        uint4 gv = *(const uint4*)(G + ((size_t)node << 6) + (sub << 3));
        float d = dinv[node];
        float4 o0 = make_float4(fmaf(acc[c][0] + bf_lo(gv.x), d, bl0.x),
                                fmaf(acc[c][1] + bf_hi(gv.x), d, bl0.y),
                                fmaf(acc[c][2] + bf_lo(gv.y), d, bl0.z),
                                fmaf(acc[c][3] + bf_hi(gv.y), d, bl0.w));
        float4 o1 = make_float4(fmaf(acc[c][4] + bf_lo(gv.z), d, bl1.x),
                                fmaf(acc[c][5] + bf_hi(gv.z), d, bl1.y),
                                fmaf(acc[c][6] + bf_lo(gv.w), d, bl1.z),
                                fmaf(acc[c][7] + bf_hi(gv.w), d, bl1.w));
        if (do_relu) {
            o0.x = fmaxf(o0.x, 0.f); o0.y = fmaxf(o0.y, 0.f);
            o0.z = fmaxf(o0.z, 0.f); o0.w = fmaxf(o0.w, 0.f);
            o1.x = fmaxf(o1.x, 0.f); o1.y = fmaxf(o1.y, 0.f);
            o1.z = fmaxf(o1.z, 0.f); o1.w = fmaxf(o1.w, 0.f);
        }
        *(float4*)(out + (size_t)node * 64 + sub * 8)     = o0;
        *(float4*)(out + (size_t)node * 64 + sub * 8 + 4) = o1;
    }
}

extern "C" void kernel_launch(void* const* d_in, const int* in_sizes, int n_in,
                              void* d_out, int out_size, void* d_ws, size_t ws_size,
                              hipStream_t stream) {
    const float* x  = (const float*)d_in[0];
    const int*   ei = (const int*)d_in[1];
    const float* W1 = (const float*)d_in[2];
    const float* b1 = (const float*)d_in[3];
    const float* W2 = (const float*)d_in[4];
    const float* b2 = (const float*)d_in[5];
    float* out = (float*)d_out;

    const int IN_CH = 128;
    const int N = in_sizes[0] / IN_CH;   // 100000
    const int E = in_sizes[1] / 2;       // 3200000
    const int* src = ei;
    const int* dst = ei + E;
    const int NB  = (N + BKT_NODES - 1) >> BKT_SHIFT;      // 196
    const int NRU = (N + (1 << RSH) - 1) >> RSH;           // 13
    const int nbin = NRU << BKT_SHIFT;                     // 6656

    char* ws = (char*)d_ws;
    size_t off = 0;
    auto take = [&](size_t bytes) -> char* {
        char* p = ws + off;
        off += (bytes + 255) & ~(size_t)255;
        return p;
    };
    float*    dinv   = (float*)take((size_t)N * 4);
    int*      bhist  = (int*)take(NBSH * 4);
    int*      boffs  = (int*)take((NBSH + 1) * 4);
    int*      bcur   = (int*)take(NBSH * 4);
    int*      rofs2  = (int*)take(((size_t)NB * nbin + 1) * 4);   // ~5.2MB
    unsigned* pairs2 = (unsigned*)take((size_t)E * 4);
    ushort_t* g      = (ushort_t*)take((size_t)E * 4);  // >= N*64*2; aliases pairs
    float*    a1     = (float*)take((size_t)N * 64 * 4);
    unsigned* pairs  = (unsigned*)g;  // pairs dead before gemm writes g

    const int nbC = (E + CHUNK - 1) / CHUNK;

    zero_small<<<1, 256, 0, stream>>>(bhist, bcur, rofs2, (size_t)NB * nbin, E);
    coarse_hist<<<nbC, 256, 0, stream>>>(dst, bhist, E, NB);
    scan196<<<1, 256, 0, stream>>>(bhist, boffs, NB, E);
    bucket_bin<<<nbC, 256, 0, stream>>>(src, dst, boffs, bcur, pairs, E, NB);
    range_scatter<<<NB, 1024, MAXB * 4, stream>>>(pairs, boffs, pairs2, rofs2, dinv, N, NRU);

    // layer 1
    gemm_scale<128><<<(N + 31) / 32, 256, 0, stream>>>(x, W1, dinv, g, N);
    aggregate4<<<NB, 1024, 0, stream>>>(g, pairs2, rofs2, dinv, b1, a1, N, 1, NRU);
    // layer 2
    gemm_scale<64><<<(N + 31) / 32, 256, 0, stream>>>(a1, W2, dinv, g, N);
    aggregate4<<<NB, 1024, 0, stream>>>(g, pairs2, rofs2, dinv, b2, out, N, 0, NRU);
}

// Round 3
// 337.518 us; speedup vs baseline: 8.7169x; 1.6785x over previous
//
#include <hip/hip_runtime.h>
#include <math.h>

// ---------------------------------------------------------------------------
// 2-layer GCN:  out = GCNConv(relu(GCNConv(x, W1, b1)), W2, b2)
// Factorization: g = (x@W) * dinv[row];  agg[d] = g[d] + sum_{s in in(d)} g[s];
//                out[d] = agg[d]*dinv[d] + b   (dinv = rsqrt(indeg+1))
//
// R1-R5: bucket sort -> LDS sort -> bf16 G rows -> dwordx4 gathers (342us,
//   aggregate 2x60us @ FETCH 162MB; 5.6 issue-cyc/edge, rest latency).
// R6: range-lockstep + LDS float atomics: FETCH 61MB (locality CONFIRMED) but
//   float LDS atomics -> CAS path, 1366us. REVERTED.
// R7: (range,node) sort + register acc: FETCH 63MB kept, but per-(node,range)
//   bins avg 2.46 edges -> unpipelinable 500cy chains, 1.9x divergence, 196
//   blocks idle 60 CUs: 168us, VALUBusy 13.6%. Bins too short for MLP.
// R8: key=(node,range) -> per-node CSR with range-ORDERED lists. Aggregate =
//   R5's proven wave-per-node shape (full grid, contiguous ~32-edge runs) at
//   4-deep gather MLP; locality via phase-correlated stratified sweeps.
//   rofs2 (5.2MB) deleted; zero_small folded into memset+scan196.
// ---------------------------------------------------------------------------

#define BKT_SHIFT 9               // 512 nodes per bucket
#define BKT_NODES 512
#define NBSH      256             // >= bucket count (196)
#define CHUNK     8192            // edges per bucket_bin/coarse_hist block
#define MAXB      20480           // max edges/bucket (mean ~16.3k)
#define RSH       13              // src range shift: ranges of 8192 nodes (1MB of G)
#define NBIN      8192            // 512 nodes * 16 range slots

typedef unsigned short ushort_t;

static __device__ __forceinline__ unsigned short f2bf(float f) {
    unsigned u = __float_as_uint(f);
    unsigned r = (u + 0x7FFFu + ((u >> 16) & 1u)) >> 16;   // RNE
    return (unsigned short)r;
}
static __device__ __forceinline__ float bf_lo(unsigned u) {
    return __uint_as_float(u << 16);
}
static __device__ __forceinline__ float bf_hi(unsigned u) {
    return __uint_as_float(u & 0xFFFF0000u);
}

struct ushort4_t { unsigned short x, y, z, w; };

// Coarse histogram over 196 buckets: LDS accumulate, 196 global atomics/block.
__global__ __launch_bounds__(256) void coarse_hist(const int* __restrict__ dst,
                                                   int* __restrict__ bhist,
                                                   int E, int NB) {
    __shared__ int h[NBSH];
    const int t  = threadIdx.x;
    const int e0 = blockIdx.x * CHUNK;
    const int n  = min(CHUNK, E - e0);
    h[t] = 0;
    __syncthreads();
    for (int i = t; i < n; i += 256) atomicAdd(&h[dst[e0 + i] >> BKT_SHIFT], 1);
    __syncthreads();
    if (t < NB && h[t] > 0) atomicAdd(&bhist[t], h[t]);
}

// Exclusive scan of bucket counts -> boffs[0..NB] (boffs[NB] = E). Also zeroes
// bcur (used by the later bucket_bin) -- absorbs the old zero_small kernel.
__global__ __launch_bounds__(256) void scan196(const int* __restrict__ bhist,
                                               int* __restrict__ boffs,
                                               int* __restrict__ bcur, int NB, int E) {
    __shared__ int sh[256];
    int t = threadIdx.x;
    bcur[t] = 0;
    int orig = (t < NB) ? bhist[t] : 0;
    sh[t] = orig;
    __syncthreads();
    for (int d = 1; d < 256; d <<= 1) {
        int u = (t >= d) ? sh[t - d] : 0;
        __syncthreads();
        sh[t] += u;
        __syncthreads();
    }
    if (t < NB) boffs[t] = sh[t] - orig;  // exclusive
    if (t == NB) boffs[NB] = E;
    if (t == 255 && NB < 255) boffs[NB] = E;
}

// Phase A: bin edges into buckets. Packed pair: (dst&511)<<17 | src  (src<2^17).
__global__ __launch_bounds__(256) void bucket_bin(const int* __restrict__ src,
                                                  const int* __restrict__ dst,
                                                  const int* __restrict__ boffs,
                                                  int* __restrict__ bcur,
                                                  unsigned* __restrict__ pairs,
                                                  int E, int NB) {
    __shared__ unsigned stag[CHUNK];   // 32KB
    __shared__ int hist[NBSH];
    __shared__ int lofs[NBSH];
    __shared__ int lcur[NBSH];
    __shared__ int gbase[NBSH];
    const int t  = threadIdx.x;
    const int e0 = blockIdx.x * CHUNK;
    const int n  = min(CHUNK, E - e0);

    for (int i = t; i < NBSH; i += 256) hist[i] = 0;
    __syncthreads();
    for (int i = t; i < n; i += 256) atomicAdd(&hist[dst[e0 + i] >> BKT_SHIFT], 1);
    __syncthreads();
    int v = hist[t];
    lofs[t] = v;
    __syncthreads();
    for (int d = 1; d < 256; d <<= 1) {
        int u = (t >= d) ? lofs[t - d] : 0;
        __syncthreads();
        lofs[t] += u;
        __syncthreads();
    }
    if (t < NB) {
        lcur[t]  = lofs[t] - v;
        gbase[t] = (v > 0) ? boffs[t] + atomicAdd(&bcur[t], v) : 0;
    }
    __syncthreads();
    for (int i = t; i < n; i += 256) {
        int d = dst[e0 + i];
        int s = src[e0 + i];
        int b = d >> BKT_SHIFT;
        int p = atomicAdd(&lcur[b], 1);
        stag[p] = ((unsigned)(d & (BKT_NODES - 1)) << 17) | (unsigned)s;
    }
    __syncthreads();
    // copy-out: wave-per-bucket (parallel across the 4 waves, 64-lane runs)
    const int wv = t >> 6, ln = t & 63;
    for (int b = wv; b < NB; b += 4) {
        int cb = hist[b];
        if (cb == 0) continue;
        int lo = lofs[b] - cb;
        int gb = gbase[b];
        for (int i = ln; i < cb; i += 64) pairs[gb + i] = stag[lo + i];
    }
}

// Phase B: per-bucket counting sort by key = (dst_node<<4) | src_range.
// Result: per-node CONTIGUOUS edge lists (CSR), each list range-ordered.
// Emits csr (=src values), per-node cnt/offs/dinv. Int LDS atomics only.
__global__ __launch_bounds__(1024) void csr_sort2(const unsigned* __restrict__ pairs,
                                                  const int* __restrict__ boffs,
                                                  unsigned* __restrict__ csr,
                                                  int* __restrict__ cnt,
                                                  int* __restrict__ offs,
                                                  float* __restrict__ dinv,
                                                  int N) {
    extern __shared__ unsigned st[];   // MAXB entries (80KB)
    __shared__ int hist2[NBIN];        // 32KB: counts -> exclusive cursors
    __shared__ int sc[1024];           // 4KB scan temp
    const int b    = blockIdx.x;
    const int t    = threadIdx.x;
    const int n0   = b << BKT_SHIFT;
    const int base = boffs[b];
    const int ne   = boffs[b + 1] - base;

    for (int i = t; i < NBIN; i += 1024) hist2[i] = 0;
    __syncthreads();
    for (int i = t; i < ne; i += 1024) {
        unsigned p = pairs[base + i];
        int key = (int)(((p >> 17) << 4) | ((p & 0x1FFFFu) >> RSH));
        atomicAdd(&hist2[key], 1);
    }
    __syncthreads();
    // per-node degree (sum of the node's 16 contiguous bins) -> cnt/dinv
    if (t < BKT_NODES) {
        int node = n0 + t;
        if (node < N) {
            int d = 0;
#pragma unroll
            for (int r = 0; r < 16; ++r) d += hist2[(t << 4) + r];
            cnt[node]  = d;
            dinv[node] = rsqrtf((float)(d + 1));
        }
    }
    __syncthreads();
    // exclusive scan over 8192 bins: 8 bins/thread, then 1024-wide scan
    int lv[8];
    int lsum = 0;
#pragma unroll
    for (int j = 0; j < 8; ++j) {
        int v = hist2[(t << 3) + j];
        lv[j] = v;
        lsum += v;
    }
    sc[t] = lsum;
    __syncthreads();
    for (int d = 1; d < 1024; d <<= 1) {
        int u = (t >= d) ? sc[t - d] : 0;
        __syncthreads();
        sc[t] += u;
        __syncthreads();
    }
    int run = sc[t] - lsum;   // exclusive over this thread's chunk
    __syncthreads();
#pragma unroll
    for (int j = 0; j < 8; ++j) {
        hist2[(t << 3) + j] = run;    // cursor = exclusive bin start
        run += lv[j];
    }
    __syncthreads();
    // per-node list start (before scatter mutates cursors)
    if (t < BKT_NODES) {
        int node = n0 + t;
        if (node < N) offs[node] = base + hist2[t << 4];
    }
    __syncthreads();
    const bool fit = (ne <= MAXB);
    for (int i = t; i < ne; i += 1024) {
        unsigned p = pairs[base + i];
        int key = (int)(((p >> 17) << 4) | ((p & 0x1FFFFu) >> RSH));
        int pos = atomicAdd(&hist2[key], 1);
        unsigned sv = p & 0x1FFFFu;
        if (fit) st[pos] = sv;
        else     csr[base + pos] = sv;   // safety fallback (uncoalesced)
    }
    if (fit) {
        __syncthreads();
        for (int i = t; i < ne; i += 1024) csr[base + i] = st[i];
    }
}

// G[row] = bf16( (X[row] @ W) * dinv[row] ).  X:[N,K] f32, W:[K,64], G:[N,64] bf16.
template <int K>
__global__ __launch_bounds__(256) void gemm_scale(const float* __restrict__ X,
                                                  const float* __restrict__ W,
                                                  const float* __restrict__ dinv,
                                                  ushort_t* __restrict__ G, int N) {
    __shared__ float Ws[K * 64];
    __shared__ float Xs[32][K + 1];
    const int t  = threadIdx.x;
    const int r0 = blockIdx.x * 32;

    for (int i = t; i < K * 16; i += 256)
        ((float4*)Ws)[i] = ((const float4*)W)[i];

    for (int i = t; i < 32 * (K / 4); i += 256) {
        int row = i / (K / 4);
        int kk  = (i % (K / 4)) * 4;
        int gr  = r0 + row;
        float4 v = make_float4(0.f, 0.f, 0.f, 0.f);
        if (gr < N) v = *(const float4*)(X + (size_t)gr * K + kk);
        Xs[row][kk + 0] = v.x; Xs[row][kk + 1] = v.y;
        Xs[row][kk + 2] = v.z; Xs[row][kk + 3] = v.w;
    }
    __syncthreads();

    const int cg = (t & 15) * 4;
    const int ry = t >> 4;
    float4 a0 = make_float4(0.f, 0.f, 0.f, 0.f);
    float4 a1 = make_float4(0.f, 0.f, 0.f, 0.f);
#pragma unroll 8
    for (int k = 0; k < K; ++k) {
        float4 w = *(const float4*)&Ws[k * 64 + cg];
        float x0 = Xs[ry][k];
        float x1 = Xs[ry + 16][k];
        a0.x = fmaf(x0, w.x, a0.x); a0.y = fmaf(x0, w.y, a0.y);
        a0.z = fmaf(x0, w.z, a0.z); a0.w = fmaf(x0, w.w, a0.w);
        a1.x = fmaf(x1, w.x, a1.x); a1.y = fmaf(x1, w.y, a1.y);
        a1.z = fmaf(x1, w.z, a1.z); a1.w = fmaf(x1, w.w, a1.w);
    }

    int row0 = r0 + ry;
    if (row0 < N) {
        float s = dinv[row0];
        ushort4_t o = { f2bf(a0.x * s), f2bf(a0.y * s), f2bf(a0.z * s), f2bf(a0.w * s) };
        *(ushort4_t*)(G + (size_t)row0 * 64 + cg) = o;
    }
    int row1 = r0 + ry + 16;
    if (row1 < N) {
        float s = dinv[row1];
        ushort4_t o = { f2bf(a1.x * s), f2bf(a1.y * s), f2bf(a1.z * s), f2bf(a1.w * s) };
        *(ushort4_t*)(G + (size_t)row1 * 64 + cg) = o;
    }
}

#define ACC8(v)                                         \
    acc[0] += bf_lo((v).x); acc[1] += bf_hi((v).x);     \
    acc[2] += bf_lo((v).y); acc[3] += bf_hi((v).y);     \
    acc[4] += bf_lo((v).z); acc[5] += bf_hi((v).z);     \
    acc[6] += bf_lo((v).w); acc[7] += bf_hi((v).w);

// Wave per node; 8 edges per gather instruction, 4 gathers in flight.
// grp=lane>>3 picks the edge, sub=lane&7 the 16B chunk of the 128B row.
// csr lists are range-ordered: co-resident waves sweep src space together.
__global__ __launch_bounds__(256) void aggregate5(const ushort_t* __restrict__ G,
                                                  const int* __restrict__ offs,
                                                  const int* __restrict__ cnt,
                                                  const unsigned* __restrict__ csr,
                                                  const float* __restrict__ dinv,
                                                  const float* __restrict__ bias,
                                                  float* __restrict__ out, int N,
                                                  int do_relu) {
    int w    = (blockIdx.x * 256 + threadIdx.x) >> 6;
    int lane = threadIdx.x & 63;
    if (w >= N) return;
    const int grp = lane >> 3;   // which edge of the batch of 8
    const int sub = lane & 7;    // which 16B chunk of the row
    const int beg = offs[w];
    const int num = cnt[w];

    float acc[8] = {0.f, 0.f, 0.f, 0.f, 0.f, 0.f, 0.f, 0.f};
    // self-loop: group 0 only
    if (grp == 0) {
        uint4 v = *(const uint4*)(G + (size_t)w * 64 + sub * 8);
        ACC8(v);
    }

    int e = 0;
    for (; e + 32 <= num; e += 32) {
        unsigned s0 = csr[beg + e + grp];
        unsigned s1 = csr[beg + e + 8 + grp];
        unsigned s2 = csr[beg + e + 16 + grp];
        unsigned s3 = csr[beg + e + 24 + grp];
        uint4 v0 = *(const uint4*)(G + ((size_t)s0 << 6) + (sub << 3));
        uint4 v1 = *(const uint4*)(G + ((size_t)s1 << 6) + (sub << 3));
        uint4 v2 = *(const uint4*)(G + ((size_t)s2 << 6) + (sub << 3));
        uint4 v3 = *(const uint4*)(G + ((size_t)s3 << 6) + (sub << 3));
        ACC8(v0); ACC8(v1); ACC8(v2); ACC8(v3);
    }
    if (e + 16 <= num) {
        unsigned s0 = csr[beg + e + grp];
        unsigned s1 = csr[beg + e + 8 + grp];
        uint4 v0 = *(const uint4*)(G + ((size_t)s0 << 6) + (sub << 3));
        uint4 v1 = *(const uint4*)(G + ((size_t)s1 << 6) + (sub << 3));
        ACC8(v0); ACC8(v1);
        e += 16;
    }
    if (e + 8 <= num) {
        unsigned s0 = csr[beg + e + grp];
        uint4 v0 = *(const uint4*)(G + ((size_t)s0 << 6) + (sub << 3));
        ACC8(v0);
        e += 8;
    }
    int rem = num - e;
    if (grp < rem) {
        unsigned s0 = csr[beg + e + grp];
        uint4 v0 = *(const uint4*)(G + ((size_t)s0 << 6) + (sub << 3));
        ACC8(v0);
    }

    // reduce across the 8 groups (lanes sharing `sub`): xor masks 8,16,32
#pragma unroll
    for (int m = 8; m <= 32; m <<= 1) {
#pragma unroll
        for (int j = 0; j < 8; ++j) acc[j] += __shfl_xor(acc[j], m, 64);
    }

    if (grp == 0) {
        float d = dinv[w];
        float4 bl0 = *(const float4*)(bias + sub * 8);
        float4 bl1 = *(const float4*)(bias + sub * 8 + 4);
        float4 o0 = make_float4(fmaf(acc[0], d, bl0.x), fmaf(acc[1], d, bl0.y),
                                fmaf(acc[2], d, bl0.z), fmaf(acc[3], d, bl0.w));
        float4 o1 = make_float4(fmaf(acc[4], d, bl1.x), fmaf(acc[5], d, bl1.y),
                                fmaf(acc[6], d, bl1.z), fmaf(acc[7], d, bl1.w));
        if (do_relu) {
            o0.x = fmaxf(o0.x, 0.f); o0.y = fmaxf(o0.y, 0.f);
            o0.z = fmaxf(o0.z, 0.f); o0.w = fmaxf(o0.w, 0.f);
            o1.x = fmaxf(o1.x, 0.f); o1.y = fmaxf(o1.y, 0.f);
            o1.z = fmaxf(o1.z, 0.f); o1.w = fmaxf(o1.w, 0.f);
        }
        *(float4*)(out + (size_t)w * 64 + sub * 8)     = o0;
        *(float4*)(out + (size_t)w * 64 + sub * 8 + 4) = o1;
    }
}

extern "C" void kernel_launch(void* const* d_in, const int* in_sizes, int n_in,
                              void* d_out, int out_size, void* d_ws, size_t ws_size,
                              hipStream_t stream) {
    const float* x  = (const float*)d_in[0];
    const int*   ei = (const int*)d_in[1];
    const float* W1 = (const float*)d_in[2];
    const float* b1 = (const float*)d_in[3];
    const float* W2 = (const float*)d_in[4];
    const float* b2 = (const float*)d_in[5];
    float* out = (float*)d_out;

    const int IN_CH = 128;
    const int N = in_sizes[0] / IN_CH;   // 100000
    const int E = in_sizes[1] / 2;       // 3200000
    const int* src = ei;
    const int* dst = ei + E;
    const int NB = (N + BKT_NODES - 1) >> BKT_SHIFT;  // 196

    char* ws = (char*)d_ws;
    size_t off = 0;
    auto take = [&](size_t bytes) -> char* {
        char* p = ws + off;
        off += (bytes + 255) & ~(size_t)255;
        return p;
    };
    float*    dinv  = (float*)take((size_t)N * 4);
    int*      cnt   = (int*)take((size_t)N * 4);
    int*      offs  = (int*)take((size_t)N * 4);
    int*      bhist = (int*)take(NBSH * 4);
    int*      boffs = (int*)take((NBSH + 1) * 4);
    int*      bcur  = (int*)take(NBSH * 4);
    unsigned* csr   = (unsigned*)take((size_t)E * 4);
    ushort_t* g     = (ushort_t*)take((size_t)E * 4);  // >= N*64*2; aliases pairs
    float*    a1    = (float*)take((size_t)N * 64 * 4);
    unsigned* pairs = (unsigned*)g;  // pairs dead before gemm writes g

    const int nbC = (E + CHUNK - 1) / CHUNK;

    hipMemsetAsync(bhist, 0, NBSH * 4, stream);
    coarse_hist<<<nbC, 256, 0, stream>>>(dst, bhist, E, NB);
    scan196<<<1, 256, 0, stream>>>(bhist, boffs, bcur, NB, E);
    bucket_bin<<<nbC, 256, 0, stream>>>(src, dst, boffs, bcur, pairs, E, NB);
    csr_sort2<<<NB, 1024, MAXB * 4, stream>>>(pairs, boffs, csr, cnt, offs, dinv, N);

    // layer 1
    gemm_scale<128><<<(N + 31) / 32, 256, 0, stream>>>(x, W1, dinv, g, N);
    aggregate5<<<(N + 3) / 4, 256, 0, stream>>>(g, offs, cnt, csr, dinv, b1, a1, N, 1);
    // layer 2
    gemm_scale<64><<<(N + 31) / 32, 256, 0, stream>>>(a1, W2, dinv, g, N);
    aggregate5<<<(N + 3) / 4, 256, 0, stream>>>(g, offs, cnt, csr, dinv, b2, out, N, 0);
}

// Round 4
// 332.495 us; speedup vs baseline: 8.8486x; 1.0151x over previous
//
#include <hip/hip_runtime.h>
#include <math.h>

// ---------------------------------------------------------------------------
// 2-layer GCN:  out = GCNConv(relu(GCNConv(x, W1, b1)), W2, b2)
// Factorization: g = (x@W) * dinv[row];  agg[d] = g[d] + sum_{s in in(d)} g[s];
//                out[d] = agg[d]*dinv[d] + b   (dinv = rsqrt(indeg+1))
//
// R1-R5: bucket sort -> LDS sort -> bf16 G rows -> dwordx4 gathers (342us).
// R6: range-lockstep + LDS float atomics: FETCH 61MB (locality confirmed) but
//   float LDS atomics take CAS path -> 1366us. REVERTED.
// R7: (range,node) bins avg 2.46 edges -> latency chains, 168us. REVERTED.
// R8: (node,range) CSR + R5-shape aggregate: 58.5us/agg but FETCH 162MB --
//   stratified-sweep locality is a no-op (2.5 edges/range/node). 337us total.
// R9: aggregate untouched (proven). Attack the invisible ~220us:
//   - gemm_scale was LDS-unit-bound (24cy LDS vs 24cy VALU per wave-k, x4
//     SIMDs share one LDS pipe). New shape: X via global float4 (L1-resident,
//     16-lane broadcast), W in LDS (1x b128/k) -> VALU-bound, ~10us floor.
//   - coarse_hist+scan196+zero deleted: fixed-stride MAXB bucket regions,
//     allocation by bcur atomics (32-sigma headroom + clamp).
//   - csr_sort back to 512 bins (range refinement proved useless in R8).
// ---------------------------------------------------------------------------

#define BKT_SHIFT 9               // 512 nodes per bucket
#define BKT_NODES 512
#define NBSH      256             // >= bucket count (196)
#define CHUNK     8192            // edges per bucket_bin block
#define MAXB      20480           // fixed per-bucket region (mean ~16.3k, 32 sigma)

typedef unsigned short ushort_t;

static __device__ __forceinline__ unsigned short f2bf(float f) {
    unsigned u = __float_as_uint(f);
    unsigned r = (u + 0x7FFFu + ((u >> 16) & 1u)) >> 16;   // RNE
    return (unsigned short)r;
}
static __device__ __forceinline__ float bf_lo(unsigned u) {
    return __uint_as_float(u << 16);
}
static __device__ __forceinline__ float bf_hi(unsigned u) {
    return __uint_as_float(u & 0xFFFF0000u);
}

struct ushort4_t { unsigned short x, y, z, w; };

// Phase A: bin edges into fixed-stride bucket regions (pairs[b*MAXB ...]).
// Packed pair: (dst&511)<<17 | src  (src < 2^17). bcur = per-bucket cursor.
__global__ __launch_bounds__(256) void bucket_bin(const int* __restrict__ src,
                                                  const int* __restrict__ dst,
                                                  int* __restrict__ bcur,
                                                  unsigned* __restrict__ pairs,
                                                  int E, int NB) {
    __shared__ unsigned stag[CHUNK];   // 32KB
    __shared__ int hist[NBSH];
    __shared__ int lofs[NBSH];
    __shared__ int lcur[NBSH];
    __shared__ int gbase[NBSH];
    const int t  = threadIdx.x;
    const int e0 = blockIdx.x * CHUNK;
    const int n  = min(CHUNK, E - e0);

    for (int i = t; i < NBSH; i += 256) hist[i] = 0;
    __syncthreads();
    for (int i = t; i < n; i += 256) atomicAdd(&hist[dst[e0 + i] >> BKT_SHIFT], 1);
    __syncthreads();
    int v = hist[t];
    lofs[t] = v;
    __syncthreads();
    for (int d = 1; d < 256; d <<= 1) {
        int u = (t >= d) ? lofs[t - d] : 0;
        __syncthreads();
        lofs[t] += u;
        __syncthreads();
    }
    if (t < NB) {
        lcur[t]  = lofs[t] - v;
        gbase[t] = (v > 0) ? t * MAXB + atomicAdd(&bcur[t], v) : 0;
    }
    __syncthreads();
    for (int i = t; i < n; i += 256) {
        int d = dst[e0 + i];
        int s = src[e0 + i];
        int b = d >> BKT_SHIFT;
        int p = atomicAdd(&lcur[b], 1);
        stag[p] = ((unsigned)(d & (BKT_NODES - 1)) << 17) | (unsigned)s;
    }
    __syncthreads();
    // copy-out: wave-per-bucket (parallel across the 4 waves, 64-lane runs)
    const int wv = t >> 6, ln = t & 63;
    for (int b = wv; b < NB; b += 4) {
        int cb = hist[b];
        if (cb == 0) continue;
        int lo = lofs[b] - cb;
        int gb = gbase[b];
        int lim = min(cb, (b + 1) * MAXB - gb);   // overflow clamp (never in practice)
        for (int i = ln; i < lim; i += 64) pairs[gb + i] = stag[lo + i];
    }
}

// Phase B: per-bucket 512-bin counting sort by dst node. Emits per-node
// contiguous csr lists (src values), cnt/offs/dinv. Int LDS atomics only.
__global__ __launch_bounds__(1024) void csr_sort(const unsigned* __restrict__ pairs,
                                                 const int* __restrict__ bcur,
                                                 unsigned* __restrict__ csr,
                                                 int* __restrict__ cnt,
                                                 int* __restrict__ offs,
                                                 float* __restrict__ dinv, int N) {
    extern __shared__ unsigned st[];   // MAXB entries (80KB)
    __shared__ int h[BKT_NODES];
    __shared__ int sc[BKT_NODES];
    __shared__ int cur[BKT_NODES];
    const int b    = blockIdx.x;
    const int t    = threadIdx.x;
    const int n0   = b << BKT_SHIFT;
    const int base = b * MAXB;
    const int ne   = min(bcur[b], MAXB);

    if (t < BKT_NODES) h[t] = 0;
    __syncthreads();
    for (int i = t; i < ne; i += 1024) atomicAdd(&h[pairs[base + i] >> 17], 1);
    __syncthreads();
    int v = 0;
    if (t < BKT_NODES) { v = h[t]; sc[t] = v; }
    __syncthreads();
    for (int d = 1; d < BKT_NODES; d <<= 1) {
        int u = (t < BKT_NODES && t >= d) ? sc[t - d] : 0;
        __syncthreads();
        if (t < BKT_NODES) sc[t] += u;
        __syncthreads();
    }
    if (t < BKT_NODES) {
        int ex = sc[t] - v;   // exclusive
        cur[t] = ex;
        int node = n0 + t;
        if (node < N) {
            cnt[node]  = v;
            offs[node] = base + ex;
            dinv[node] = rsqrtf((float)(v + 1));
        }
    }
    __syncthreads();
    for (int i = t; i < ne; i += 1024) {
        unsigned p = pairs[base + i];
        int pos = atomicAdd(&cur[p >> 17], 1);
        st[pos] = p & 0x1FFFFu;
    }
    __syncthreads();
    for (int i = t; i < ne; i += 1024) csr[base + i] = st[i];
}

// G[row] = bf16( (X[row] @ W) * dinv[row] ).  X:[N,K] f32, W:[K,64], G:[N,64] bf16.
// Thread tile: 8 rows x 4 cols. X read as global float4 (16-lane broadcast,
// block footprint 128 rows x 128B = 16KB -> L1-resident). W from LDS: one
// ds_read_b128 per k per thread (2-way bank aliasing = free). VALU-bound.
template <int K>
__global__ __launch_bounds__(256) void gemm_scale(const float* __restrict__ X,
                                                  const float* __restrict__ W,
                                                  const float* __restrict__ dinv,
                                                  ushort_t* __restrict__ G, int N) {
    __shared__ float Ws[K * 64];
    const int t  = threadIdx.x;
    const int r0 = blockIdx.x * 128;

    for (int i = t; i < K * 16; i += 256)
        ((float4*)Ws)[i] = ((const float4*)W)[i];

    const int cg = (t & 15) * 4;           // column group
    const int rb = r0 + (t >> 4) * 8;      // first of this thread's 8 rows

    float acc[8][4];
#pragma unroll
    for (int j = 0; j < 8; ++j) {
        acc[j][0] = 0.f; acc[j][1] = 0.f; acc[j][2] = 0.f; acc[j][3] = 0.f;
    }
    __syncthreads();

    const bool full = (rb + 8 <= N);
    for (int k = 0; k < K; k += 4) {
        float4 xr[8];
        if (full) {
#pragma unroll
            for (int j = 0; j < 8; ++j)
                xr[j] = *(const float4*)(X + (size_t)(rb + j) * K + k);
        } else {
#pragma unroll
            for (int j = 0; j < 8; ++j)
                xr[j] = (rb + j < N) ? *(const float4*)(X + (size_t)(rb + j) * K + k)
                                     : make_float4(0.f, 0.f, 0.f, 0.f);
        }
#pragma unroll
        for (int kk = 0; kk < 4; ++kk) {
            float4 w = *(const float4*)&Ws[(k + kk) * 64 + cg];
#pragma unroll
            for (int j = 0; j < 8; ++j) {
                float xv = (&xr[j].x)[kk];
                acc[j][0] = fmaf(xv, w.x, acc[j][0]);
                acc[j][1] = fmaf(xv, w.y, acc[j][1]);
                acc[j][2] = fmaf(xv, w.z, acc[j][2]);
                acc[j][3] = fmaf(xv, w.w, acc[j][3]);
            }
        }
    }

#pragma unroll
    for (int j = 0; j < 8; ++j) {
        int row = rb + j;
        if (row < N) {
            float s = dinv[row];
            ushort4_t o = { f2bf(acc[j][0] * s), f2bf(acc[j][1] * s),
                            f2bf(acc[j][2] * s), f2bf(acc[j][3] * s) };
            *(ushort4_t*)(G + (size_t)row * 64 + cg) = o;
        }
    }
}

#define ACC8(v)                                         \
    acc[0] += bf_lo((v).x); acc[1] += bf_hi((v).x);     \
    acc[2] += bf_lo((v).y); acc[3] += bf_hi((v).y);     \
    acc[4] += bf_lo((v).z); acc[5] += bf_hi((v).z);     \
    acc[6] += bf_lo((v).w); acc[7] += bf_hi((v).w);

// Wave per node; 8 edges per gather instruction, 4 gathers in flight.
// grp=lane>>3 picks the edge, sub=lane&7 the 16B chunk of the 128B row.
// PROVEN shape (R5/R8: 58.5us, VALU 51%) -- unchanged.
__global__ __launch_bounds__(256) void aggregate5(const ushort_t* __restrict__ G,
                                                  const int* __restrict__ offs,
                                                  const int* __restrict__ cnt,
                                                  const unsigned* __restrict__ csr,
                                                  const float* __restrict__ dinv,
                                                  const float* __restrict__ bias,
                                                  float* __restrict__ out, int N,
                                                  int do_relu) {
    int w    = (blockIdx.x * 256 + threadIdx.x) >> 6;
    int lane = threadIdx.x & 63;
    if (w >= N) return;
    const int grp = lane >> 3;   // which edge of the batch of 8
    const int sub = lane & 7;    // which 16B chunk of the row
    const int beg = offs[w];
    const int num = cnt[w];

    float acc[8] = {0.f, 0.f, 0.f, 0.f, 0.f, 0.f, 0.f, 0.f};
    // self-loop: group 0 only
    if (grp == 0) {
        uint4 v = *(const uint4*)(G + (size_t)w * 64 + sub * 8);
        ACC8(v);
    }

    int e = 0;
    for (; e + 32 <= num; e += 32) {
        unsigned s0 = csr[beg + e + grp];
        unsigned s1 = csr[beg + e + 8 + grp];
        unsigned s2 = csr[beg + e + 16 + grp];
        unsigned s3 = csr[beg + e + 24 + grp];
        uint4 v0 = *(const uint4*)(G + ((size_t)s0 << 6) + (sub << 3));
        uint4 v1 = *(const uint4*)(G + ((size_t)s1 << 6) + (sub << 3));
        uint4 v2 = *(const uint4*)(G + ((size_t)s2 << 6) + (sub << 3));
        uint4 v3 = *(const uint4*)(G + ((size_t)s3 << 6) + (sub << 3));
        ACC8(v0); ACC8(v1); ACC8(v2); ACC8(v3);
    }
    if (e + 16 <= num) {
        unsigned s0 = csr[beg + e + grp];
        unsigned s1 = csr[beg + e + 8 + grp];
        uint4 v0 = *(const uint4*)(G + ((size_t)s0 << 6) + (sub << 3));
        uint4 v1 = *(const uint4*)(G + ((size_t)s1 << 6) + (sub << 3));
        ACC8(v0); ACC8(v1);
        e += 16;
    }
    if (e + 8 <= num) {
        unsigned s0 = csr[beg + e + grp];
        uint4 v0 = *(const uint4*)(G + ((size_t)s0 << 6) + (sub << 3));
        ACC8(v0);
        e += 8;
    }
    int rem = num - e;
    if (grp < rem) {
        unsigned s0 = csr[beg + e + grp];
        uint4 v0 = *(const uint4*)(G + ((size_t)s0 << 6) + (sub << 3));
        ACC8(v0);
    }

    // reduce across the 8 groups (lanes sharing `sub`): xor masks 8,16,32
#pragma unroll
    for (int m = 8; m <= 32; m <<= 1) {
#pragma unroll
        for (int j = 0; j < 8; ++j) acc[j] += __shfl_xor(acc[j], m, 64);
    }

    if (grp == 0) {
        float d = dinv[w];
        float4 bl0 = *(const float4*)(bias + sub * 8);
        float4 bl1 = *(const float4*)(bias + sub * 8 + 4);
        float4 o0 = make_float4(fmaf(acc[0], d, bl0.x), fmaf(acc[1], d, bl0.y),
                                fmaf(acc[2], d, bl0.z), fmaf(acc[3], d, bl0.w));
        float4 o1 = make_float4(fmaf(acc[4], d, bl1.x), fmaf(acc[5], d, bl1.y),
                                fmaf(acc[6], d, bl1.z), fmaf(acc[7], d, bl1.w));
        if (do_relu) {
            o0.x = fmaxf(o0.x, 0.f); o0.y = fmaxf(o0.y, 0.f);
            o0.z = fmaxf(o0.z, 0.f); o0.w = fmaxf(o0.w, 0.f);
            o1.x = fmaxf(o1.x, 0.f); o1.y = fmaxf(o1.y, 0.f);
            o1.z = fmaxf(o1.z, 0.f); o1.w = fmaxf(o1.w, 0.f);
        }
        *(float4*)(out + (size_t)w * 64 + sub * 8)     = o0;
        *(float4*)(out + (size_t)w * 64 + sub * 8 + 4) = o1;
    }
}

extern "C" void kernel_launch(void* const* d_in, const int* in_sizes, int n_in,
                              void* d_out, int out_size, void* d_ws, size_t ws_size,
                              hipStream_t stream) {
    const float* x  = (const float*)d_in[0];
    const int*   ei = (const int*)d_in[1];
    const float* W1 = (const float*)d_in[2];
    const float* b1 = (const float*)d_in[3];
    const float* W2 = (const float*)d_in[4];
    const float* b2 = (const float*)d_in[5];
    float* out = (float*)d_out;

    const int IN_CH = 128;
    const int N = in_sizes[0] / IN_CH;   // 100000
    const int E = in_sizes[1] / 2;       // 3200000
    const int* src = ei;
    const int* dst = ei + E;
    const int NB = (N + BKT_NODES - 1) >> BKT_SHIFT;  // 196

    char* ws = (char*)d_ws;
    size_t off = 0;
    auto take = [&](size_t bytes) -> char* {
        char* p = ws + off;
        off += (bytes + 255) & ~(size_t)255;
        return p;
    };
    float*    dinv  = (float*)take((size_t)N * 4);
    int*      cnt   = (int*)take((size_t)N * 4);
    int*      offs  = (int*)take((size_t)N * 4);
    int*      bcur  = (int*)take(NBSH * 4);
    unsigned* csr   = (unsigned*)take((size_t)NB * MAXB * 4);   // 16.06MB
    ushort_t* g     = (ushort_t*)take((size_t)N * 64 * 2);      // 12.8MB
    float*    a1    = (float*)take((size_t)N * 64 * 4);         // 25.6MB
    unsigned* pairs = (unsigned*)a1;   // NB*MAXB*4 <= N*64*4; dead before agg1 writes a1

    const int nbC = (E + CHUNK - 1) / CHUNK;

    hipMemsetAsync(bcur, 0, NBSH * 4, stream);
    bucket_bin<<<nbC, 256, 0, stream>>>(src, dst, bcur, pairs, E, NB);
    csr_sort<<<NB, 1024, MAXB * 4, stream>>>(pairs, bcur, csr, cnt, offs, dinv, N);

    // layer 1
    gemm_scale<128><<<(N + 127) / 128, 256, 0, stream>>>(x, W1, dinv, g, N);
    aggregate5<<<(N + 3) / 4, 256, 0, stream>>>(g, offs, cnt, csr, dinv, b1, a1, N, 1);
    // layer 2
    gemm_scale<64><<<(N + 127) / 128, 256, 0, stream>>>(a1, W2, dinv, g, N);
    aggregate5<<<(N + 3) / 4, 256, 0, stream>>>(g, offs, cnt, csr, dinv, b2, out, N, 0);
}